// Round 8
// baseline (234.860 us; speedup 1.0000x reference)
//
#include <hip/hip_runtime.h>

// VQ-VAE vector quantizer, MI355X (gfx950).
//   inputs : z (8,256,16,16,16) fp32, codebook (1024,256) fp32
//   output : quant (8,256,16,16,16) ++ idx (8,16,16,16) ++ loss (1), fp32 flat
//
// Round 14: PHASE-SPLIT for measurement + occupancy shaping. Six structural
//   rewrites (r7-r13: staging/barriers/occupancy/z-gathers/dep-chains) all
//   landed within +-15% of 135us with every pipe <25% busy -- the monolithic
//   kernel hides where the time goes. Split into three dispatches so rocprof
//   reports per-phase dur/counters:
//     C: Sz + A-frags + MFMA filter (r13's verified paired-ct form),
//        spills cnt/cand/Sz(=fadd(Szp0,Szp1), bit-identical) to ws.
//     D: barrier-free, LDS-free exact recheck (256thr x 1024 blocks,
//        16 waves/CU). Prune dropped: rechecks ALL appended candidates --
//        strict superset of the pruned set => identical lex-min (D,k).
//        Overflow full-scan preserved. Writes idx to out.
//     E: epilogue (r6/r8-verified form): e-row float4 gather, quant store,
//        loss atomic + last-block publish. Reads idx from out.
//   All exact fp32 chains (Sz/Se/dot/D/lex-min/loss) bit-identical to r13.

#define K_CODES 1024
#define DIM 256
#define N_TOK 32768
#define SPATIAL 4096
#define TOK_BLK 64
#define NBLK (N_TOK / TOK_BLK)
#define CAP 28
#define MARGIN 1e-3f

typedef __attribute__((ext_vector_type(8))) short short8;
typedef __attribute__((ext_vector_type(4))) float float4v;

// ws layout in floats
#define WS_LOSS 0
#define WS_CNT 8         // unsigned completion counter (E blocks)
#define WS_E2 16         // 1024 floats: Se[k] (np pairwise)
#define WS_EB 2048       // 262144 bf16: codebook, B-fragment order
#define WS_SZ 133120     // 32768 floats: Sz per token (blk0+blk1 combined)
#define WS_CAND 165888   // 32768*28 u16 candidate ids (458752 floats)
#define WS_CCNT 624640   // 32768 ints: candidate counts (raw, may exceed CAP)

#define O_IDX (8 * DIM * SPATIAL)  // 8388608
#define O_LOSS (O_IDX + N_TOK)     // 8421376

__device__ __forceinline__ short f2bf(float v) {  // RTNE fp32->bf16 bits
  unsigned u = __float_as_uint(v);
  u = (u + 0x7fffu + ((u >> 16) & 1u)) >> 16;
  return (short)u;
}

// prep: Se[k] np-pairwise (exact order, parallelized); codebook -> bf16 in
// MFMA B-fragment order, 16B chunk stores.  (verified rounds 7-13)
__global__ __launch_bounds__(256) void prep_kernel(const float* __restrict__ e,
                                                   float* __restrict__ ws) {
  __shared__ float sq[DIM];
  __shared__ __align__(16) short sbf[DIM];
  __shared__ float chv[16];
  int k = blockIdx.x, d = threadIdx.x;
  float v = e[k * DIM + d];
  sbf[d] = f2bf(v);
  sq[d] = __fmul_rn(v, v);
  __syncthreads();
  if (d < 32) {  // 16B chunk stores of the fragment layout
    int f = d >> 2, q = d & 3;
    int stage = k >> 6, ct = (k >> 4) & 3, nn = k & 15;
    short8 chunk = *(const short8*)(sbf + f * 32 + q * 8);
    int off8 = ((stage * 4 + ct) * 8 + f) * 64 + q * 16 + nn;
    ((short8*)(ws + WS_EB))[off8] = chunk;
  }
  if (d < 16) {  // chain (blk=d>>3, j=d&7): exact np serial order i=0..15
    int blkb = d >> 3, j = d & 7;
    const float* x = sq + blkb * 128;
    float c = x[j];
#pragma unroll
    for (int i = 1; i < 16; i++) c = __fadd_rn(c, x[i * 8 + j]);
    chv[d] = c;
  }
  __syncthreads();
  if (d == 0) {  // exact np_pairwise128 combine tree, then blk0+blk1
    float a0 = __fadd_rn(__fadd_rn(chv[0], chv[1]), __fadd_rn(chv[2], chv[3]));
    float a1 = __fadd_rn(__fadd_rn(chv[4], chv[5]), __fadd_rn(chv[6], chv[7]));
    float resA = __fadd_rn(a0, a1);
    float b0 = __fadd_rn(__fadd_rn(chv[8], chv[9]), __fadd_rn(chv[10], chv[11]));
    float b1 = __fadd_rn(__fadd_rn(chv[12], chv[13]), __fadd_rn(chv[14], chv[15]));
    float resB = __fadd_rn(b0, b1);
    ws[WS_E2 + k] = __fadd_rn(resA, resB);
    if (k == 0) {
      ws[WS_LOSS] = 0.f;
      ((unsigned*)ws)[WS_CNT] = 0u;
    }
  }
}

// ---- Kernel C: Sz + A-frags + MFMA filter (r13's verified form), spill ----
__global__ __launch_bounds__(512, 4) void filter_kernel(const float* __restrict__ z,
                                                        float* __restrict__ ws) {
  __shared__ __align__(16) short Bst[64 * 256];  // 32 KB, fragment order
  __shared__ unsigned short cand[TOK_BLK][CAP];
  __shared__ int cnt[TOK_BLK];
  __shared__ float Szp[2][TOK_BLK];  // per-128-dim-block Sz partials

  int tid = threadIdx.x, w = tid >> 6, lane = tid & 63;
  int quad = lane >> 4, nn = lane & 15;
  int g = w & 3, kh = w >> 2;  // token group (16 tokens), codebook half
  int n0 = blockIdx.x * TOK_BLK;
  int b = n0 >> 12, s0 = n0 & 4095;
  const float* zb = z + (size_t)b * DIM * SPATIAL + s0;
  const float* Se = ws + WS_E2;
  const uint4* eBg = (const uint4*)(ws + WS_EB);
  if (tid < TOK_BLK) cnt[tid] = 0;

  // ---- Sz partial (exact np pairwise): wave kh does dim-block kh (128 d)
  //      for its 16 tokens; merge tree = exact np pairing (r8/r11-verified) ----
  {
    const float* zp = zb + g * 16 + nn;
    float r0, r1;
    {
      int j0 = quad * 2;
      float v0 = zp[(size_t)(kh * 128 + j0) * SPATIAL];
      float v1 = zp[(size_t)(kh * 128 + j0 + 1) * SPATIAL];
      r0 = __fmul_rn(v0, v0);
      r1 = __fmul_rn(v1, v1);
      for (int i = 1; i < 16; i++) {
        v0 = zp[(size_t)(kh * 128 + i * 8 + j0) * SPATIAL];
        v1 = zp[(size_t)(kh * 128 + i * 8 + j0 + 1) * SPATIAL];
        r0 = __fadd_rn(r0, __fmul_rn(v0, v0));
        r1 = __fadd_rn(r1, __fmul_rn(v1, v1));
      }
    }
    float p = __fadd_rn(r0, r1);                    // (c_{2q} + c_{2q+1})
    float s1 = __fadd_rn(p, __shfl_xor(p, 16));     // (p0+p1) | (p2+p3)
    float s2 = __fadd_rn(s1, __shfl_xor(s1, 32));   // np_pairwise128 result
    if (quad == 0) Szp[kh][g * 16 + nn] = s2;
  }

  // ---- A fragments (z -> bf16): token m = g*16+nn, frag f holds
  //      k-dim d = f*32 + quad*8 + j ----
  int tokA = g * 16 + nn;
  short8 A[8];
#pragma unroll
  for (int f = 0; f < 8; f++) {
    short8 a;
#pragma unroll
    for (int j = 0; j < 8; j++) {
      int d = f * 32 + quad * 8 + j;
      a[j] = f2bf(zb[(size_t)d * SPATIAL + tokA]);
    }
    A[f] = a;
  }

  // ---- Phase C: MFMA filter, 16 stages, paired cts (r13-verified) ----
  float thr[4] = {3.4e38f, 3.4e38f, 3.4e38f, 3.4e38f};
  for (int stage = 0; stage < 16; stage++) {
    __syncthreads();  // prior-stage LDS reads done (also orders cnt=0, Szp)
#pragma unroll
    for (int i = 0; i < 4; i++)  // 32 KB via 512 threads: reg round-trip
      ((uint4*)Bst)[i * 512 + tid] = eBg[(size_t)stage * 2048 + i * 512 + tid];
    __syncthreads();  // data ready

    int ct0 = kh * 2, ct1 = kh * 2 + 1;
    int kbase0 = stage * 64 + ct0 * 16;
    int kbase1 = stage * 64 + ct1 * 16;
    float4v C0 = {0.f, 0.f, 0.f, 0.f};
    float4v C1 = {0.f, 0.f, 0.f, 0.f};
    const short8* Bp0 = (const short8*)Bst + ct0 * 8 * 64;
    const short8* Bp1 = (const short8*)Bst + ct1 * 8 * 64;
#pragma unroll
    for (int f = 0; f < 8; f++) {  // two independent chains, interleaved
      short8 B0 = Bp0[f * 64 + lane];  // ds_read_b128, conflict-free
      short8 B1 = Bp1[f * 64 + lane];
      C0 = __builtin_amdgcn_mfma_f32_16x16x32_bf16(A[f], B0, C0, 0, 0, 0);
      C1 = __builtin_amdgcn_mfma_f32_16x16x32_bf16(A[f], B1, C1, 0, 0, 0);
    }
    float SeK0 = Se[kbase0 + nn];  // col = code = nn
    float SeK1 = Se[kbase1 + nn];
    float s0v[4], s1v[4], m0[4], m1[4];
#pragma unroll
    for (int r = 0; r < 4; r++) {  // row = token = quad*4 + r
      s0v[r] = fmaf(-2.f, C0[r], SeK0);
      s1v[r] = fmaf(-2.f, C1[r], SeK1);
      m0[r] = s0v[r];
      m1[r] = s1v[r];
    }
#pragma unroll
    for (int dlt = 1; dlt <= 8; dlt <<= 1) {  // 8 independent rowmin chains
#pragma unroll
      for (int r = 0; r < 4; r++) {
        m0[r] = fminf(m0[r], __shfl_xor(m0[r], dlt, 16));
        m1[r] = fminf(m1[r], __shfl_xor(m1[r], dlt, 16));
      }
    }
    // ---- ct0: thr update + append (r11/r13 order) ----
    bool pr[4];
#pragma unroll
    for (int r = 0; r < 4; r++) {
      thr[r] = fminf(thr[r], m0[r]);
      pr[r] = s0v[r] < thr[r] + MARGIN;
    }
    if (__ballot(pr[0] | pr[1] | pr[2] | pr[3])) {  // rare path
#pragma unroll
      for (int r = 0; r < 4; r++) {
        unsigned long long bl = __ballot(pr[r]);
        unsigned grp = (unsigned)((bl >> (quad * 16)) & 0xffffULL);
        if (grp) {  // quad-uniform
          int tb = g * 16 + quad * 4 + r;
          int base = 0;
          if (nn == 0) base = atomicAdd(&cnt[tb], __popc(grp));
          base = __shfl(base, quad * 16);  // broadcast from quad's lane 0
          if (pr[r]) {
            int pos = base + __popc(grp & ((1u << nn) - 1u));
            if (pos < CAP) cand[tb][pos] = (unsigned short)(kbase0 + nn);
          }
        }
      }
    }
    // ---- ct1: thr update + append ----
#pragma unroll
    for (int r = 0; r < 4; r++) {
      thr[r] = fminf(thr[r], m1[r]);
      pr[r] = s1v[r] < thr[r] + MARGIN;
    }
    if (__ballot(pr[0] | pr[1] | pr[2] | pr[3])) {  // rare path
#pragma unroll
      for (int r = 0; r < 4; r++) {
        unsigned long long bl = __ballot(pr[r]);
        unsigned grp = (unsigned)((bl >> (quad * 16)) & 0xffffULL);
        if (grp) {  // quad-uniform
          int tb = g * 16 + quad * 4 + r;
          int base = 0;
          if (nn == 0) base = atomicAdd(&cnt[tb], __popc(grp));
          base = __shfl(base, quad * 16);  // broadcast from quad's lane 0
          if (pr[r]) {
            int pos = base + __popc(grp & ((1u << nn) - 1u));
            if (pos < CAP) cand[tb][pos] = (unsigned short)(kbase1 + nn);
          }
        }
      }
    }
  }
  __syncthreads();  // cnt + cand complete across all waves

  // ---- spill per-token state: token t = tid>>3, slot j = tid&7 ----
  {
    int t = tid >> 3, j = tid & 7;
    int cv = cnt[t];
    if (j == 0) ((int*)ws)[WS_CCNT + n0 + t] = cv;
    if (j == 1)  // Sz total: exact blk0+blk1 (same op D used in r11/r13)
      ws[WS_SZ + n0 + t] = __fadd_rn(Szp[0][t], Szp[1][t]);
    int cl = cv < CAP ? cv : CAP;
    unsigned short* cg = (unsigned short*)(ws + WS_CAND) + (size_t)(n0 + t) * CAP;
    for (int c = j; c < cl; c += 8) cg[c] = cand[t][c];
  }
}

// ---- Kernel D: exact recheck, barrier-free, no LDS. Block = 256 thr =
//      4 waves x 8 tokens; grid 1024. Rechecks ALL candidates (prune
//      dropped -- superset => identical lex-min (D,k)). ----
__global__ __launch_bounds__(256, 8) void recheck_kernel(const float* __restrict__ z,
                                                         const float* __restrict__ e,
                                                         float* __restrict__ ws,
                                                         float* __restrict__ out) {
  int tid = threadIdx.x, w = tid >> 6, lane = tid & 63;
  int tl = lane >> 3, oct = lane & 7;
  int n0 = blockIdx.x * 32;
  int b = n0 >> 12, s0 = n0 & 4095;
  const float* zb = z + (size_t)b * DIM * SPATIAL + s0;
  const float* Se = ws + WS_E2;
  const unsigned short* candg = (const unsigned short*)(ws + WS_CAND);
  const int* cntg = (const int*)ws + WS_CCNT;

  int tb = w * 8 + tl;        // local token 0..31
  int tok = n0 + tb;          // global token
  int cc = cntg[tok];
  int cl = cc < CAP ? cc : CAP;
  float Szn = ws[WS_SZ + tok];
  float bestD = 3.4e38f;
  int bestk = 0x7fffffff;
  {
    const float* zp = zb + tb;
    const unsigned short* cg = candg + (size_t)tok * CAP;
    for (int c = oct; c < cl; c += 8) {
      int k = cg[c];
      const float* er = e + (size_t)k * DIM;
      float acc = 0.f;
#pragma unroll 4
      for (int dd = 0; dd < DIM; dd += 4) {
        float4 e4 = *(const float4*)(er + dd);
        acc = fmaf(zp[(size_t)(dd + 0) * SPATIAL], e4.x, acc);
        acc = fmaf(zp[(size_t)(dd + 1) * SPATIAL], e4.y, acc);
        acc = fmaf(zp[(size_t)(dd + 2) * SPATIAL], e4.z, acc);
        acc = fmaf(zp[(size_t)(dd + 3) * SPATIAL], e4.w, acc);
      }
      float D = __fsub_rn(__fadd_rn(Szn, Se[k]), __fmul_rn(2.f, acc));
      if (D < bestD || (D == bestD && k < bestk)) { bestD = D; bestk = k; }
    }
  }
#pragma unroll
  for (int off = 4; off >= 1; off >>= 1) {  // merge the 8 lanes per token
    float oD = __shfl_down(bestD, off, 8);
    int ok = __shfl_down(bestk, off, 8);
    if (oD < bestD || (oD == bestD && ok < bestk)) { bestD = oD; bestk = ok; }
  }
  if (oct == 0 && cc <= CAP) out[O_IDX + tok] = (float)bestk;
  // overflow tokens: exact full scan by the whole wave (deterministic)
  for (int t = 0; t < 8; t++) {
    int tb2 = w * 8 + t;
    if (cntg[n0 + tb2] > CAP) {
      const float* zq = zb + tb2;
      float Sz2 = ws[WS_SZ + n0 + tb2];
      float bD = 3.4e38f;
      int bk = 0x7fffffff;
      for (int k = lane; k < K_CODES; k += 64) {
        const float* er = e + (size_t)k * DIM;
        float acc = 0.f;
#pragma unroll 4
        for (int dd = 0; dd < DIM; dd += 4) {
          float4 e4 = *(const float4*)(er + dd);
          acc = fmaf(zq[(size_t)(dd + 0) * SPATIAL], e4.x, acc);
          acc = fmaf(zq[(size_t)(dd + 1) * SPATIAL], e4.y, acc);
          acc = fmaf(zq[(size_t)(dd + 2) * SPATIAL], e4.z, acc);
          acc = fmaf(zq[(size_t)(dd + 3) * SPATIAL], e4.w, acc);
        }
        float D = __fsub_rn(__fadd_rn(Sz2, Se[k]), __fmul_rn(2.f, acc));
        if (D < bD || (D == bD && k < bk)) { bD = D; bk = k; }
      }
#pragma unroll
      for (int m = 1; m < 64; m <<= 1) {
        float oD = __shfl_xor(bD, m);
        int ok = __shfl_xor(bk, m);
        if (oD < bD || (oD == bD && ok < bk)) { bD = oD; bk = ok; }
      }
      if (lane == 0) out[O_IDX + n0 + tb2] = (float)bk;
    }
  }
}

// ---- Kernel E: quant gather + store + loss (r6/r8-verified structure) ----
__global__ __launch_bounds__(256, 4) void epilogue_kernel(const float* __restrict__ z,
                                                          const float* __restrict__ e,
                                                          float* __restrict__ ws,
                                                          float* __restrict__ out) {
  __shared__ float red[4];
  int tid = threadIdx.x, w = tid >> 6, lane = tid & 63;
  int n0 = blockIdx.x * TOK_BLK;
  int b = n0 >> 12, s0 = n0 & 4095;
  const float* zb = z + (size_t)b * DIM * SPATIAL + s0;
  int mten = (int)out[O_IDX + n0 + lane];  // lane = token
  const float* erow = e + (size_t)mten * DIM;
  float* op = out + (size_t)b * DIM * SPATIAL + s0;
  float sumsq = 0.f;
#pragma unroll 4
  for (int i4 = 0; i4 < 64; i4 += 4) {
    int d = w * 64 + i4;  // wave-uniform d, 16B-aligned
    float4 v4 = *(const float4*)(erow + d);
#pragma unroll
    for (int m = 0; m < 4; m++) {
      float v = (m == 0) ? v4.x : (m == 1) ? v4.y : (m == 2) ? v4.z : v4.w;
      float zv = zb[(size_t)(d + m) * SPATIAL + lane];
      float df = __fsub_rn(v, zv);
      sumsq = fmaf(df, df, sumsq);
      op[(size_t)(d + m) * SPATIAL + lane] = v;  // coalesced 64-wide store
    }
  }
#pragma unroll
  for (int o = 32; o > 0; o >>= 1) sumsq += __shfl_down(sumsq, o, 64);
  if (lane == 0) red[w] = sumsq;
  __syncthreads();
  if (tid == 0) {
    atomicAdd(ws + WS_LOSS, red[0] + red[1] + red[2] + red[3]);
    __threadfence();  // loss add globally visible before counter bump
    unsigned t = atomicAdd((unsigned*)ws + WS_CNT, 1u);
    if (t == NBLK - 1) {  // last E block publishes loss
      float total = atomicAdd(ws + WS_LOSS, 0.f);  // device-scope read
      out[O_LOSS] = 1.25f * total / 8388608.f;
    }
  }
}

extern "C" void kernel_launch(void* const* d_in, const int* in_sizes, int n_in,
                              void* d_out, int out_size, void* d_ws, size_t ws_size,
                              hipStream_t stream) {
  const float* z = (const float*)d_in[0];
  const float* e = (const float*)d_in[1];
  float* ws = (float*)d_ws;
  float* out = (float*)d_out;

  prep_kernel<<<K_CODES, 256, 0, stream>>>(e, ws);
  filter_kernel<<<NBLK, 512, 0, stream>>>(z, ws);
  recheck_kernel<<<N_TOK / 32, 256, 0, stream>>>(z, e, ws, out);
  epilogue_kernel<<<NBLK, 256, 0, stream>>>(z, e, ws, out);
}

// Round 9
// 205.204 us; speedup vs baseline: 1.1445x; 1.1445x over previous
//
#include <hip/hip_runtime.h>

// VQ-VAE vector quantizer, MI355X (gfx950).
//   inputs : z (8,256,16,16,16) fp32, codebook (1024,256) fp32
//   output : quant (8,256,16,16,16) ++ idx (8,16,16,16) ++ loss (1), fp32 flat
//
// Round 15: r14's split measured C=71us, D=70us(!), monolith 135 = C+D
//   serialized. D's cost: per-lane serial 256-fmaf chains fed by SCALAR
//   16KB-strided z loads (32B useful/wave-instr). Fix: fuse D+E into one
//   kernel per 64-token block that stages the z-slab (64x256 fp32, 66KB LDS,
//   r12-verified loader, 257-pad) ONCE coalesced; recheck dots read z from
//   LDS (broadcast/conflict-free), epilogue reads the same slab (2-way-free)
//   and writes quant coalesced. z read once per DE block; 4->3 launches.
//   prep + filter byte-identical to r14 (verified). Recheck = r14's
//   all-candidate superset lex-min (order-independent); epilogue = r13's
//   verified 8-wave form. All exact fp32 chains unchanged.

#define K_CODES 1024
#define DIM 256
#define N_TOK 32768
#define SPATIAL 4096
#define TOK_BLK 64
#define NBLK (N_TOK / TOK_BLK)
#define CAP 28
#define MARGIN 1e-3f
#define ZLD 257  // z-slab row stride (floats): bank = (tok + d) % 32

typedef __attribute__((ext_vector_type(8))) short short8;
typedef __attribute__((ext_vector_type(4))) float float4v;

// ws layout in floats
#define WS_LOSS 0
#define WS_CNT 8         // unsigned completion counter (DE blocks)
#define WS_E2 16         // 1024 floats: Se[k] (np pairwise)
#define WS_EB 2048       // 262144 bf16: codebook, B-fragment order
#define WS_SZ 133120     // 32768 floats: Sz per token (blk0+blk1 combined)
#define WS_CAND 165888   // 32768*28 u16 candidate ids (458752 floats)
#define WS_CCNT 624640   // 32768 ints: candidate counts (raw, may exceed CAP)

#define O_IDX (8 * DIM * SPATIAL)  // 8388608
#define O_LOSS (O_IDX + N_TOK)     // 8421376

__device__ __forceinline__ short f2bf(float v) {  // RTNE fp32->bf16 bits
  unsigned u = __float_as_uint(v);
  u = (u + 0x7fffu + ((u >> 16) & 1u)) >> 16;
  return (short)u;
}

// prep: Se[k] np-pairwise (exact order, parallelized); codebook -> bf16 in
// MFMA B-fragment order, 16B chunk stores.  (verified rounds 7-14)
__global__ __launch_bounds__(256) void prep_kernel(const float* __restrict__ e,
                                                   float* __restrict__ ws) {
  __shared__ float sq[DIM];
  __shared__ __align__(16) short sbf[DIM];
  __shared__ float chv[16];
  int k = blockIdx.x, d = threadIdx.x;
  float v = e[k * DIM + d];
  sbf[d] = f2bf(v);
  sq[d] = __fmul_rn(v, v);
  __syncthreads();
  if (d < 32) {  // 16B chunk stores of the fragment layout
    int f = d >> 2, q = d & 3;
    int stage = k >> 6, ct = (k >> 4) & 3, nn = k & 15;
    short8 chunk = *(const short8*)(sbf + f * 32 + q * 8);
    int off8 = ((stage * 4 + ct) * 8 + f) * 64 + q * 16 + nn;
    ((short8*)(ws + WS_EB))[off8] = chunk;
  }
  if (d < 16) {  // chain (blk=d>>3, j=d&7): exact np serial order i=0..15
    int blkb = d >> 3, j = d & 7;
    const float* x = sq + blkb * 128;
    float c = x[j];
#pragma unroll
    for (int i = 1; i < 16; i++) c = __fadd_rn(c, x[i * 8 + j]);
    chv[d] = c;
  }
  __syncthreads();
  if (d == 0) {  // exact np_pairwise128 combine tree, then blk0+blk1
    float a0 = __fadd_rn(__fadd_rn(chv[0], chv[1]), __fadd_rn(chv[2], chv[3]));
    float a1 = __fadd_rn(__fadd_rn(chv[4], chv[5]), __fadd_rn(chv[6], chv[7]));
    float resA = __fadd_rn(a0, a1);
    float b0 = __fadd_rn(__fadd_rn(chv[8], chv[9]), __fadd_rn(chv[10], chv[11]));
    float b1 = __fadd_rn(__fadd_rn(chv[12], chv[13]), __fadd_rn(chv[14], chv[15]));
    float resB = __fadd_rn(b0, b1);
    ws[WS_E2 + k] = __fadd_rn(resA, resB);
    if (k == 0) {
      ws[WS_LOSS] = 0.f;
      ((unsigned*)ws)[WS_CNT] = 0u;
    }
  }
}

// ---- Kernel C: Sz + A-frags + MFMA filter (r13/r14-verified), spill ----
__global__ __launch_bounds__(512, 4) void filter_kernel(const float* __restrict__ z,
                                                        float* __restrict__ ws) {
  __shared__ __align__(16) short Bst[64 * 256];  // 32 KB, fragment order
  __shared__ unsigned short cand[TOK_BLK][CAP];
  __shared__ int cnt[TOK_BLK];
  __shared__ float Szp[2][TOK_BLK];  // per-128-dim-block Sz partials

  int tid = threadIdx.x, w = tid >> 6, lane = tid & 63;
  int quad = lane >> 4, nn = lane & 15;
  int g = w & 3, kh = w >> 2;  // token group (16 tokens), codebook half
  int n0 = blockIdx.x * TOK_BLK;
  int b = n0 >> 12, s0 = n0 & 4095;
  const float* zb = z + (size_t)b * DIM * SPATIAL + s0;
  const float* Se = ws + WS_E2;
  const uint4* eBg = (const uint4*)(ws + WS_EB);
  if (tid < TOK_BLK) cnt[tid] = 0;

  // ---- Sz partial (exact np pairwise): wave kh does dim-block kh (128 d)
  //      for its 16 tokens; merge tree = exact np pairing (r8/r11-verified) ----
  {
    const float* zp = zb + g * 16 + nn;
    float r0, r1;
    {
      int j0 = quad * 2;
      float v0 = zp[(size_t)(kh * 128 + j0) * SPATIAL];
      float v1 = zp[(size_t)(kh * 128 + j0 + 1) * SPATIAL];
      r0 = __fmul_rn(v0, v0);
      r1 = __fmul_rn(v1, v1);
      for (int i = 1; i < 16; i++) {
        v0 = zp[(size_t)(kh * 128 + i * 8 + j0) * SPATIAL];
        v1 = zp[(size_t)(kh * 128 + i * 8 + j0 + 1) * SPATIAL];
        r0 = __fadd_rn(r0, __fmul_rn(v0, v0));
        r1 = __fadd_rn(r1, __fmul_rn(v1, v1));
      }
    }
    float p = __fadd_rn(r0, r1);                    // (c_{2q} + c_{2q+1})
    float s1 = __fadd_rn(p, __shfl_xor(p, 16));     // (p0+p1) | (p2+p3)
    float s2 = __fadd_rn(s1, __shfl_xor(s1, 32));   // np_pairwise128 result
    if (quad == 0) Szp[kh][g * 16 + nn] = s2;
  }

  // ---- A fragments (z -> bf16): token m = g*16+nn, frag f holds
  //      k-dim d = f*32 + quad*8 + j ----
  int tokA = g * 16 + nn;
  short8 A[8];
#pragma unroll
  for (int f = 0; f < 8; f++) {
    short8 a;
#pragma unroll
    for (int j = 0; j < 8; j++) {
      int d = f * 32 + quad * 8 + j;
      a[j] = f2bf(zb[(size_t)d * SPATIAL + tokA]);
    }
    A[f] = a;
  }

  // ---- Phase C: MFMA filter, 16 stages, paired cts (r13-verified) ----
  float thr[4] = {3.4e38f, 3.4e38f, 3.4e38f, 3.4e38f};
  for (int stage = 0; stage < 16; stage++) {
    __syncthreads();  // prior-stage LDS reads done (also orders cnt=0, Szp)
#pragma unroll
    for (int i = 0; i < 4; i++)  // 32 KB via 512 threads: reg round-trip
      ((uint4*)Bst)[i * 512 + tid] = eBg[(size_t)stage * 2048 + i * 512 + tid];
    __syncthreads();  // data ready

    int ct0 = kh * 2, ct1 = kh * 2 + 1;
    int kbase0 = stage * 64 + ct0 * 16;
    int kbase1 = stage * 64 + ct1 * 16;
    float4v C0 = {0.f, 0.f, 0.f, 0.f};
    float4v C1 = {0.f, 0.f, 0.f, 0.f};
    const short8* Bp0 = (const short8*)Bst + ct0 * 8 * 64;
    const short8* Bp1 = (const short8*)Bst + ct1 * 8 * 64;
#pragma unroll
    for (int f = 0; f < 8; f++) {  // two independent chains, interleaved
      short8 B0 = Bp0[f * 64 + lane];  // ds_read_b128, conflict-free
      short8 B1 = Bp1[f * 64 + lane];
      C0 = __builtin_amdgcn_mfma_f32_16x16x32_bf16(A[f], B0, C0, 0, 0, 0);
      C1 = __builtin_amdgcn_mfma_f32_16x16x32_bf16(A[f], B1, C1, 0, 0, 0);
    }
    float SeK0 = Se[kbase0 + nn];  // col = code = nn
    float SeK1 = Se[kbase1 + nn];
    float s0v[4], s1v[4], m0[4], m1[4];
#pragma unroll
    for (int r = 0; r < 4; r++) {  // row = token = quad*4 + r
      s0v[r] = fmaf(-2.f, C0[r], SeK0);
      s1v[r] = fmaf(-2.f, C1[r], SeK1);
      m0[r] = s0v[r];
      m1[r] = s1v[r];
    }
#pragma unroll
    for (int dlt = 1; dlt <= 8; dlt <<= 1) {  // 8 independent rowmin chains
#pragma unroll
      for (int r = 0; r < 4; r++) {
        m0[r] = fminf(m0[r], __shfl_xor(m0[r], dlt, 16));
        m1[r] = fminf(m1[r], __shfl_xor(m1[r], dlt, 16));
      }
    }
    // ---- ct0: thr update + append (r11/r13 order) ----
    bool pr[4];
#pragma unroll
    for (int r = 0; r < 4; r++) {
      thr[r] = fminf(thr[r], m0[r]);
      pr[r] = s0v[r] < thr[r] + MARGIN;
    }
    if (__ballot(pr[0] | pr[1] | pr[2] | pr[3])) {  // rare path
#pragma unroll
      for (int r = 0; r < 4; r++) {
        unsigned long long bl = __ballot(pr[r]);
        unsigned grp = (unsigned)((bl >> (quad * 16)) & 0xffffULL);
        if (grp) {  // quad-uniform
          int tb = g * 16 + quad * 4 + r;
          int base = 0;
          if (nn == 0) base = atomicAdd(&cnt[tb], __popc(grp));
          base = __shfl(base, quad * 16);  // broadcast from quad's lane 0
          if (pr[r]) {
            int pos = base + __popc(grp & ((1u << nn) - 1u));
            if (pos < CAP) cand[tb][pos] = (unsigned short)(kbase0 + nn);
          }
        }
      }
    }
    // ---- ct1: thr update + append ----
#pragma unroll
    for (int r = 0; r < 4; r++) {
      thr[r] = fminf(thr[r], m1[r]);
      pr[r] = s1v[r] < thr[r] + MARGIN;
    }
    if (__ballot(pr[0] | pr[1] | pr[2] | pr[3])) {  // rare path
#pragma unroll
      for (int r = 0; r < 4; r++) {
        unsigned long long bl = __ballot(pr[r]);
        unsigned grp = (unsigned)((bl >> (quad * 16)) & 0xffffULL);
        if (grp) {  // quad-uniform
          int tb = g * 16 + quad * 4 + r;
          int base = 0;
          if (nn == 0) base = atomicAdd(&cnt[tb], __popc(grp));
          base = __shfl(base, quad * 16);  // broadcast from quad's lane 0
          if (pr[r]) {
            int pos = base + __popc(grp & ((1u << nn) - 1u));
            if (pos < CAP) cand[tb][pos] = (unsigned short)(kbase1 + nn);
          }
        }
      }
    }
  }
  __syncthreads();  // cnt + cand complete across all waves

  // ---- spill per-token state: token t = tid>>3, slot j = tid&7 ----
  {
    int t = tid >> 3, j = tid & 7;
    int cv = cnt[t];
    if (j == 0) ((int*)ws)[WS_CCNT + n0 + t] = cv;
    if (j == 1)  // Sz total: exact blk0+blk1 (same op D uses; bit-identical)
      ws[WS_SZ + n0 + t] = __fadd_rn(Szp[0][t], Szp[1][t]);
    int cl = cv < CAP ? cv : CAP;
    unsigned short* cg = (unsigned short*)(ws + WS_CAND) + (size_t)(n0 + t) * CAP;
    for (int c = j; c < cl; c += 8) cg[c] = cand[t][c];
  }
}

// ---- Kernel DE: z-slab to LDS once, exact recheck from LDS, epilogue.
//      512 thr, 64 tokens/block, grid NBLK; 66KB LDS -> 2 blocks/CU. ----
__global__ __launch_bounds__(512, 4) void de_kernel(const float* __restrict__ z,
                                                    const float* __restrict__ e,
                                                    float* __restrict__ ws,
                                                    float* __restrict__ out) {
  __shared__ float zs[TOK_BLK * ZLD];  // 64 x 257 fp32 z-slab (66 KB)
  __shared__ int mini_sh[TOK_BLK];
  __shared__ float red[8];

  int tid = threadIdx.x, w = tid >> 6, lane = tid & 63;
  int n0 = blockIdx.x * TOK_BLK;
  int b = n0 >> 12, s0 = n0 & 4095;
  const float* zb = z + (size_t)b * DIM * SPATIAL + s0;
  const float* Se = ws + WS_E2;
  const unsigned short* candg = (const unsigned short*)(ws + WS_CAND);
  const int* cntg = (const int*)ws + WS_CCNT;

  // ---- z-slab load (r12-verified): 4096 float4 chunks, coalesced along
  //      tokens; chunk c -> d = c>>4, tok4 = (c&15)*4 ----
#pragma unroll
  for (int it = 0; it < 8; it++) {
    int c = it * 512 + tid;
    int d = c >> 4, t4 = (c & 15) << 2;
    float4 v4 = *(const float4*)(zb + (size_t)d * SPATIAL + t4);
    zs[(t4 + 0) * ZLD + d] = v4.x;
    zs[(t4 + 1) * ZLD + d] = v4.y;
    zs[(t4 + 2) * ZLD + d] = v4.z;
    zs[(t4 + 3) * ZLD + d] = v4.w;
  }
  __syncthreads();  // slab ready

  // ---- D-part: exact recheck from LDS. Wave w owns tokens w*8..w*8+7;
  //      lane = (token tl, oct); slots oct::8. All candidates rechecked
  //      (superset => identical lex-min). fmaf chain exact ascending d. ----
  int tl = lane >> 3, oct = lane & 7;
  int tb = w * 8 + tl;
  int tok = n0 + tb;
  int cc = cntg[tok];
  int cl = cc < CAP ? cc : CAP;
  float Szn = ws[WS_SZ + tok];
  float bestD = 3.4e38f;
  int bestk = 0x7fffffff;
  {
    const float* zp = zs + tb * ZLD;
    const unsigned short* cg = candg + (size_t)tok * CAP;
    for (int c = oct; c < cl; c += 8) {
      int k = cg[c];
      const float* er = e + (size_t)k * DIM;
      float acc = 0.f;
#pragma unroll 4
      for (int dd = 0; dd < DIM; dd += 4) {
        float4 e4 = *(const float4*)(er + dd);
        acc = fmaf(zp[dd + 0], e4.x, acc);
        acc = fmaf(zp[dd + 1], e4.y, acc);
        acc = fmaf(zp[dd + 2], e4.z, acc);
        acc = fmaf(zp[dd + 3], e4.w, acc);
      }
      float D = __fsub_rn(__fadd_rn(Szn, Se[k]), __fmul_rn(2.f, acc));
      if (D < bestD || (D == bestD && k < bestk)) { bestD = D; bestk = k; }
    }
  }
#pragma unroll
  for (int off = 4; off >= 1; off >>= 1) {  // merge the 8 lanes per token
    float oD = __shfl_down(bestD, off, 8);
    int ok = __shfl_down(bestk, off, 8);
    if (oD < bestD || (oD == bestD && ok < bestk)) { bestD = oD; bestk = ok; }
  }
  if (oct == 0 && cc <= CAP) {
    mini_sh[tb] = bestk;
    out[O_IDX + tok] = (float)bestk;
  }
  // overflow tokens: exact full scan by the whole wave (deterministic)
  for (int t = 0; t < 8; t++) {
    int tb2 = w * 8 + t;
    if (cntg[n0 + tb2] > CAP) {
      const float* zq = zs + tb2 * ZLD;
      float Sz2 = ws[WS_SZ + n0 + tb2];
      float bD = 3.4e38f;
      int bk = 0x7fffffff;
      for (int k = lane; k < K_CODES; k += 64) {
        const float* er = e + (size_t)k * DIM;
        float acc = 0.f;
#pragma unroll 4
        for (int dd = 0; dd < DIM; dd += 4) {
          float4 e4 = *(const float4*)(er + dd);
          acc = fmaf(zq[dd + 0], e4.x, acc);
          acc = fmaf(zq[dd + 1], e4.y, acc);
          acc = fmaf(zq[dd + 2], e4.z, acc);
          acc = fmaf(zq[dd + 3], e4.w, acc);
        }
        float D = __fsub_rn(__fadd_rn(Sz2, Se[k]), __fmul_rn(2.f, acc));
        if (D < bD || (D == bD && k < bk)) { bD = D; bk = k; }
      }
#pragma unroll
      for (int m = 1; m < 64; m <<= 1) {
        float oD = __shfl_xor(bD, m);
        int ok = __shfl_xor(bk, m);
        if (oD < bD || (oD == bD && ok < bk)) { bD = oD; bk = ok; }
      }
      if (lane == 0) {
        mini_sh[tb2] = bk;
        out[O_IDX + n0 + tb2] = (float)bk;
      }
    }
  }
  __syncthreads();  // mini_sh ready

  // ---- E-part (r13-verified form): lane = token; wave w covers dims
  //      [w*32, w*32+32); z from slab ((lane+d)%32 -> 2-way-free) ----
  int mten = mini_sh[lane];
  const float* erow = e + (size_t)mten * DIM;
  const float* zrow = zs + lane * ZLD;
  float* op = out + (size_t)b * DIM * SPATIAL + s0;
  float sumsq = 0.f;
#pragma unroll 2
  for (int i4 = 0; i4 < 32; i4 += 4) {
    int d = w * 32 + i4;  // wave-uniform d, 16B-aligned
    float4 v4 = *(const float4*)(erow + d);
#pragma unroll
    for (int m = 0; m < 4; m++) {
      float v = (m == 0) ? v4.x : (m == 1) ? v4.y : (m == 2) ? v4.z : v4.w;
      float zv = zrow[d + m];
      float df = __fsub_rn(v, zv);
      sumsq = fmaf(df, df, sumsq);
      op[(size_t)(d + m) * SPATIAL + lane] = v;  // coalesced 64-wide store
    }
  }
#pragma unroll
  for (int o = 32; o > 0; o >>= 1) sumsq += __shfl_down(sumsq, o, 64);
  if (lane == 0) red[w] = sumsq;
  __syncthreads();
  if (tid == 0) {
    float rs = ((red[0] + red[1]) + (red[2] + red[3])) +
               ((red[4] + red[5]) + (red[6] + red[7]));
    atomicAdd(ws + WS_LOSS, rs);
    __threadfence();  // loss add globally visible before counter bump
    unsigned t = atomicAdd((unsigned*)ws + WS_CNT, 1u);
    if (t == NBLK - 1) {  // last DE block publishes loss
      float total = atomicAdd(ws + WS_LOSS, 0.f);  // device-scope read
      out[O_LOSS] = 1.25f * total / 8388608.f;
    }
  }
}

extern "C" void kernel_launch(void* const* d_in, const int* in_sizes, int n_in,
                              void* d_out, int out_size, void* d_ws, size_t ws_size,
                              hipStream_t stream) {
  const float* z = (const float*)d_in[0];
  const float* e = (const float*)d_in[1];
  float* ws = (float*)d_ws;
  float* out = (float*)d_out;

  prep_kernel<<<K_CODES, 256, 0, stream>>>(e, ws);
  filter_kernel<<<NBLK, 512, 0, stream>>>(z, ws);
  de_kernel<<<NBLK, 512, 0, stream>>>(z, e, ws, out);
}